// Round 13
// baseline (104.080 us; speedup 1.0000x reference)
//
#include <hip/hip_runtime.h>
#include <math.h>

// Problem constants
#define BB   4
#define CC   128
#define HH   64
#define WW   64
#define OUTC 128
#define KK   25     // 5x5 attention taps
#define PXB  16     // pixels per block (quarter row)
#define SJ   20     // staged cols: 16 + 4 halo

typedef __attribute__((ext_vector_type(8))) short short8;   // 8 bf16
typedef _Float16 half8  __attribute__((ext_vector_type(8)));
typedef __fp16   fp16x2 __attribute__((ext_vector_type(2))); // cvt_pkrtz ret
typedef __attribute__((ext_vector_type(4))) float floatx4;  // MFMA acc

__device__ __forceinline__ unsigned short f32_to_bf16(float v) {
    unsigned int u = __float_as_uint(v);
    u += 0x7fffu + ((u >> 16) & 1u);          // RNE
    return (unsigned short)(u >> 16);
}

// ---------------------------------------------------------------------------
// Kernel 0 (prep): identical to round 12 (verified).
//  i < 16384:        w2o[o][c] = bf16( sum_r w2[o, c*4+r] )  (o-major, MFMA A)
//  16384..+36864:    w1f = conv1 weights as fp16 in MFMA A-fragment lane
//                    order: w1f[(((dydx*2+mt)*4+ks)*64+lane)*8+i8]
// ---------------------------------------------------------------------------
__global__ void prep_kernel(const float* __restrict__ w2,
                            const float* __restrict__ w1,
                            unsigned short* __restrict__ w2o,
                            unsigned short* __restrict__ w1f) {
    int i = blockIdx.x * 256 + threadIdx.x;
    if (i < 16384) {
        int o = i >> 7, c = i & 127;
        const float* p = w2 + o * (4 * CC) + c * 4;
        w2o[o * CC + c] = f32_to_bf16(p[0] + p[1] + p[2] + p[3]);
    } else if (i < 16384 + 36864) {
        int f = i - 16384;            // 0..36863
        int i8   = f & 7;
        int lane = (f >> 3) & 63;
        int ks   = (f >> 9) & 3;
        int mt   = (f >> 11) & 1;
        int dydx = f >> 12;           // 0..8
        int kk = mt * 16 + (lane & 15);
        int c  = ks * 32 + (lane >> 4) * 8 + i8;
        float v = (kk < KK) ? w1[(size_t)(kk * CC + c) * 9 + dydx] : 0.f;
        _Float16 hv = (_Float16)v;    // RNE
        w1f[f] = *(unsigned short*)&hv;
    }
}

// ---------------------------------------------------------------------------
// Fused kernel: conv1-as-MFMA(fp16) + softmax + attention + MFMA + 2x2 store.
// grid 1024 = (b, h, wq): 16-px quarter-row, 128 threads (2 waves).
//
// ROUND 12 POST-MORTEM: fused ~40us inferred (dur = fill 44 + prep + fused
// + ~8 gaps), still ~8x the work-sum -> latency-exposed at 2 waves/SIMD.
// Biggest remaining global-latency population: phase C's 120 global float2
// loads/thread (~300cy L2). THIS ROUND: stage 5 rows (h-2..h+2) in ONE
// [r][j][c] fp16 buffer (25.6KB, still 4 blocks/CU) serving BOTH conv
// (rows 1..3, contiguous-c MFMA B-frags) AND phase C (per-c ds_read_u16,
// ~40cy, no masks -- borders zero-staged). x@fp16 in phase C adds ~2^-11
// rel err, far below sKT's bf16 quantization -> absmax unchanged.
// LDS: xs 25.6KB + pk 1.6KB + sKT 4.4KB = 31.6KB (sKT now separate:
// xs stays live through phase C). __launch_bounds__(128,2): proven.
// ---------------------------------------------------------------------------
__global__ __launch_bounds__(128, 2) void fused_kernel(
        const float* __restrict__ x,
        const unsigned short* __restrict__ w1f,
        const unsigned short* __restrict__ w2o,
        const float* __restrict__ b1,
        const float* __restrict__ b2,
        float* __restrict__ out) {
    __shared__ _Float16 xs[5 * SJ * 128];            // 25600 B
    __shared__ float pk[KK * PXB];                   // 1600 B
    __shared__ unsigned short sKT[PXB * 136];        // 4352 B

    // XCD swizzle (1024 % 8 == 0 -> bijective)
    int bid0 = blockIdx.x;
    int bid  = (bid0 & 7) * 128 + (bid0 >> 3);
    int wq = bid & 3;
    int h  = (bid >> 2) & 63;
    int b  = bid >> 8;
    int t  = threadIdx.x;
    int lane = t & 63;
    int wv = t >> 6;                 // 0..1

    const float* xb = x + (size_t)b * CC * (HH * WW);

    // ---- stage x rows h-2..h+2 as fp16, transposed+swizzled ----
    {
        // main cols: lane = (jj 0..15 -> col, cp 0..3 -> c-pair).
        int jj = lane & 15, cp = lane >> 4;
        int j  = jj + 2;
        int swz = (j & 15) << 3;
        #pragma unroll
        for (int ci = 0; ci < 8; ++ci) {
            int c  = wv * 64 + ci * 8 + cp * 2;      // even
            int cs = c ^ swz;                        // bit0 preserved
            const float* xc0 = xb + (size_t)c * (HH * WW) + wq * 16 + jj;
            const float* xc1 = xc0 + HH * WW;
            #pragma unroll
            for (int r = 0; r < 5; ++r) {
                int y = h - 2 + r;
                float v0 = 0.f, v1 = 0.f;
                if (y >= 0 && y < HH) { v0 = xc0[y * WW]; v1 = xc1[y * WW]; }
                fp16x2 p = __builtin_amdgcn_cvt_pkrtz(v0, v1);
                *(fp16x2*)&xs[(r * SJ + j) * 128 + cs] = p;
            }
        }
        // halo cols j in {0,1,18,19} (xcol = 16wq + {-2,-1,16,17})
        for (int i = t; i < 5 * 4 * 128; i += 128) {
            int jh = i & 3;
            int c  = (i >> 2) & 127;
            int r  = i >> 9;
            int j2 = (jh < 2) ? jh : 16 + jh;
            int xcol = wq * 16 + j2 - 2;
            int y = h - 2 + r;
            float v = (xcol >= 0 && xcol < WW && y >= 0 && y < HH)
                    ? xb[(size_t)c * (HH * WW) + y * WW + xcol] : 0.f;
            xs[(r * SJ + j2) * 128 + (c ^ ((j2 & 15) << 3))] = (_Float16)v;
        }
    }
    __syncthreads();

    // ---- conv1 via MFMA fp16: D[kk][px] = sum_{c,dy,dx} w1*x ----
    int fpx = lane & 15, quad = lane >> 4;
    int mt = wv;
    floatx4 acc = {0.f, 0.f, 0.f, 0.f};
    #pragma unroll
    for (int dydx = 0; dydx < 9; ++dydx) {
        int r   = dydx / 3;                      // 0..2 -> staged row r+1
        int dxm = dydx - 3 * r;
        int j   = fpx + dxm + 1;                 // staged col, 1..18
        int rowbase = ((r + 1) * SJ + j) * 128;
        int swz = (j & 15) << 3;
        const unsigned short* whb = w1f + (dydx * 2 + mt) * 2048 + lane * 8;
        #pragma unroll
        for (int ks = 0; ks < 4; ++ks) {
            int cb = (ks * 32 + quad * 8) ^ swz;
            half8 A = *(const half8*)(whb + ks * 512);
            half8 B = *(const half8*)&xs[rowbase + cb];
            acc = __builtin_amdgcn_mfma_f32_16x16x32_f16(A, B, acc, 0, 0, 0);
        }
    }
    #pragma unroll
    for (int reg = 0; reg < 4; ++reg) {          // D row = quad*4+reg
        int kk = mt * 16 + quad * 4 + reg;
        if (kk < KK) pk[kk * PXB + fpx] = acc[reg] + b1[kk];
    }
    __syncthreads();   // pk ready; xs stays live for phase C

    // ---- phase C: in-register softmax + attention from LDS ----
    // thread = (pp2 = t&7 -> px {2pp2, 2pp2+1}, cw = t>>3 -> 8 chunks of c)
    int pp2 = t & 7, cw = t >> 3;

    float2 lg[KK];
    #pragma unroll
    for (int k = 0; k < KK; ++k) lg[k] = *(const float2*)&pk[k * PXB + 2 * pp2];
    float m0 = -1e30f, m1 = -1e30f;
    #pragma unroll
    for (int k = 0; k < KK; ++k) { m0 = fmaxf(m0, lg[k].x); m1 = fmaxf(m1, lg[k].y); }
    float s0 = 0.f, s1 = 0.f;
    #pragma unroll
    for (int k = 0; k < KK; ++k) {
        lg[k].x = __expf(lg[k].x - m0); s0 += lg[k].x;
        lg[k].y = __expf(lg[k].y - m1); s1 += lg[k].y;
    }
    float i0 = 1.f / s0, i1 = 1.f / s1;
    #pragma unroll
    for (int k = 0; k < KK; ++k) { lg[k].x *= i0; lg[k].y *= i1; }

    #pragma unroll 2
    for (int i8 = 0; i8 < 8; ++i8) {
        int c = i8 * 16 + cw;
        // 30 LDS u16 reads: rows 0..4, cols j = 2pp2 .. 2pp2+5 (zero-padded
        // borders were staged -> no masks, no clamps)
        float xv[5][6];
        #pragma unroll
        for (int r = 0; r < 5; ++r)
            #pragma unroll
            for (int dj = 0; dj < 6; ++dj) {
                int j = 2 * pp2 + dj;
                xv[r][dj] = (float)xs[(r * SJ + j) * 128
                                      + (c ^ ((j & 15) << 3))];
            }
        float t0 = 0.f, t1 = 0.f;
        #pragma unroll
        for (int di = 0; di < 5; ++di)
            #pragma unroll
            for (int dj = 0; dj < 5; ++dj) {
                t0 += lg[di * 5 + dj].x * xv[di][dj];
                t1 += lg[di * 5 + dj].y * xv[di][dj + 1];
            }
        sKT[(2 * pp2) * 136 + c]     = f32_to_bf16(t0);
        sKT[(2 * pp2 + 1) * 136 + c] = f32_to_bf16(t1);
    }
    __syncthreads();

    // ---- MFMA2: C[o][px] = sum_c W2s[o][c] * s[c][px] ----
    // wave wv owns o-rows [64wv, 64wv+64): 4 o-tiles x 4 ks = 16 MFMA.
    floatx4 am[4] = {{0.f,0.f,0.f,0.f},{0.f,0.f,0.f,0.f},
                     {0.f,0.f,0.f,0.f},{0.f,0.f,0.f,0.f}};
    #pragma unroll
    for (int ks = 0; ks < 4; ++ks) {
        short8 bf = *(const short8*)&sKT[fpx * 136 + ks*32 + quad*8];
        #pragma unroll
        for (int mt2 = 0; mt2 < 4; ++mt2) {
            short8 af = *(const short8*)&w2o[(size_t)(64*wv + 16*mt2 + fpx) * CC
                                             + ks*32 + quad*8];
            am[mt2] = __builtin_amdgcn_mfma_f32_16x16x32_bf16(af, bf, am[mt2], 0, 0, 0);
        }
    }

    // ---- epilogue: D[row=quad*4+reg][col=fpx] + b2, 2x2-replicated write ----
    float* ob = out + (size_t)b * OUTC * (4 * HH * WW);
    int y0 = 2 * h;
    int pxo = wq * 16 + fpx;
    #pragma unroll
    for (int mt2 = 0; mt2 < 4; ++mt2) {
        #pragma unroll
        for (int reg = 0; reg < 4; ++reg) {
            int o = 64*wv + 16*mt2 + quad*4 + reg;
            float v = am[mt2][reg] + b2[o];
            float2 v2 = make_float2(v, v);
            float* r0p = ob + ((size_t)o * (2*HH) + y0) * (2*WW) + 2*pxo;
            *(float2*)(r0p)        = v2;
            *(float2*)(r0p + 2*WW) = v2;
        }
    }
}

// ---------------------------------------------------------------------------
extern "C" void kernel_launch(void* const* d_in, const int* in_sizes, int n_in,
                              void* d_out, int out_size, void* d_ws, size_t ws_size,
                              hipStream_t stream) {
    const float* x  = (const float*)d_in[0];
    const float* w1 = (const float*)d_in[1];
    const float* b1 = (const float*)d_in[2];
    const float* w2 = (const float*)d_in[3];
    const float* b2 = (const float*)d_in[4];
    float* out = (float*)d_out;

    unsigned short* w2o = (unsigned short*)d_ws;               // 32 KB
    unsigned short* w1f = w2o + (size_t)OUTC * CC;             // 72 KB

    prep_kernel<<<(16384 + 36864 + 255) / 256, 256, 0, stream>>>(w2, w1, w2o, w1f);
    fused_kernel<<<BB * HH * 4, 128, 0, stream>>>(x, w1f, w2o, b1, b2, out);
}

// Round 14
// 97.300 us; speedup vs baseline: 1.0697x; 1.0697x over previous
//
#include <hip/hip_runtime.h>
#include <math.h>

// Problem constants
#define BB   4
#define CC   128
#define HH   64
#define WW   64
#define OUTC 128
#define KK   25     // 5x5 attention taps
#define PXB  16     // pixels per block (quarter row)
#define SJ   20     // staged cols: 16 + 4 halo

typedef __attribute__((ext_vector_type(8))) short short8;   // 8 bf16
typedef _Float16 half8  __attribute__((ext_vector_type(8)));
typedef __fp16   fp16x2 __attribute__((ext_vector_type(2))); // cvt_pkrtz ret
typedef __attribute__((ext_vector_type(4))) float floatx4;  // MFMA acc

__device__ __forceinline__ unsigned short f32_to_bf16(float v) {
    unsigned int u = __float_as_uint(v);
    u += 0x7fffu + ((u >> 16) & 1u);          // RNE
    return (unsigned short)(u >> 16);
}

// ---------------------------------------------------------------------------
// Kernel 0 (prep): identical to round 12 (verified).
//  i < 16384:        w2o[o][c] = bf16( sum_r w2[o, c*4+r] )  (o-major, MFMA A)
//  16384..+36864:    w1f = conv1 weights as fp16 in MFMA A-fragment lane
//                    order: w1f[(((dydx*2+mt)*4+ks)*64+lane)*8+i8]
// ---------------------------------------------------------------------------
__global__ void prep_kernel(const float* __restrict__ w2,
                            const float* __restrict__ w1,
                            unsigned short* __restrict__ w2o,
                            unsigned short* __restrict__ w1f) {
    int i = blockIdx.x * 256 + threadIdx.x;
    if (i < 16384) {
        int o = i >> 7, c = i & 127;
        const float* p = w2 + o * (4 * CC) + c * 4;
        w2o[o * CC + c] = f32_to_bf16(p[0] + p[1] + p[2] + p[3]);
    } else if (i < 16384 + 36864) {
        int f = i - 16384;            // 0..36863
        int i8   = f & 7;
        int lane = (f >> 3) & 63;
        int ks   = (f >> 9) & 3;
        int mt   = (f >> 11) & 1;
        int dydx = f >> 12;           // 0..8
        int kk = mt * 16 + (lane & 15);
        int c  = ks * 32 + (lane >> 4) * 8 + i8;
        float v = (kk < KK) ? w1[(size_t)(kk * CC + c) * 9 + dydx] : 0.f;
        _Float16 hv = (_Float16)v;    // RNE
        w1f[f] = *(unsigned short*)&hv;
    }
}

// ---------------------------------------------------------------------------
// Fused kernel: conv1-as-MFMA(fp16) + softmax + attention + MFMA + 2x2 store.
// grid 1024 = (b, h, wq): 16-px quarter-row, 128 threads (2 waves).
// BASE = round 12 (best: 94.9 total; r13's LDS phase C regressed, reverted).
//
// THIS ROUND: barrier-pinned PREFETCH of every load whose data does not
// depend on the preceding barrier (LLVM cannot sink loads across
// __syncthreads, so early issue is guaranteed placement):
//  (a) phase-C chunks 0+1 (30 float2 of x) issued BEFORE the conv MFMA
//      loop -> their ~300-600cy L2 latency hides under conv+softmax;
//  (b) MFMA2's 16 w2o A-fragments + 16 b2 scalars issued right after the
//      conv accumulator is done, BEFORE the pk barrier -> hide under
//      softmax + all of phase C;
//  (c) b1 values preloaded at kernel start (pk-write dependence).
// VGPR peak ~200-220 < 256 cap of __launch_bounds__(128,2) -> no spill
// (the r3/5/6 spill regime was caps <= 128).
// LDS: xs 15KB + pk 1.6KB = 17KB; sKT overlays xs after conv.
// ---------------------------------------------------------------------------
__global__ __launch_bounds__(128, 2) void fused_kernel(
        const float* __restrict__ x,
        const unsigned short* __restrict__ w1f,
        const unsigned short* __restrict__ w2o,
        const float* __restrict__ b1,
        const float* __restrict__ b2,
        float* __restrict__ out) {
    __shared__ _Float16 xs[3 * SJ * 128];            // 15360 B
    __shared__ float pk[KK * PXB];                   // 1600 B
    unsigned short* sKT = (unsigned short*)xs;       // 16x136 bf16 overlay

    // XCD swizzle (1024 % 8 == 0 -> bijective)
    int bid0 = blockIdx.x;
    int bid  = (bid0 & 7) * 128 + (bid0 >> 3);
    int wq = bid & 3;
    int h  = (bid >> 2) & 63;
    int b  = bid >> 8;
    int t  = threadIdx.x;
    int lane = t & 63;
    int wv = t >> 6;                 // 0..1
    int fpx = lane & 15, quad = lane >> 4;
    int pp2 = t & 7, cw = t >> 3;    // phase-C thread mapping

    const float* xb = x + (size_t)b * CC * (HH * WW);

    // ---- (c) b1 preload for the pk write ----
    float b1r[4];
    #pragma unroll
    for (int reg = 0; reg < 4; ++reg) {
        int kk = wv * 16 + quad * 4 + reg;
        b1r[reg] = (kk < KK) ? b1[kk] : 0.f;
    }

    // ---- phase-C window geometry (pure VALU, needed by prefetch) ----
    int colg = wq * 16 + 2 * pp2 - 2;
    int coff[3]; float cmask[3];
    #pragma unroll
    for (int jx = 0; jx < 3; ++jx) {
        int cg = colg + 2 * jx;
        cmask[jx] = (cg >= 0 && cg <= WW - 2) ? 1.f : 0.f;
        coff[jx]  = min(max(cg, 0), WW - 2);
    }
    int yoff[5]; float msk[15];
    #pragma unroll
    for (int di = 0; di < 5; ++di) {
        int y = h + di - 2;
        float rm = (y >= 0 && y < HH) ? 1.f : 0.f;
        yoff[di] = min(max(y, 0), HH - 1) * WW;
        #pragma unroll
        for (int jx = 0; jx < 3; ++jx) msk[di * 3 + jx] = rm * cmask[jx];
    }

    // ---- stage x rows h-1..h+1 as fp16, transposed+swizzled ----
    {
        int jj = lane & 15, cp = lane >> 4;
        int j  = jj + 2;
        int swz = (j & 15) << 3;
        #pragma unroll
        for (int ci = 0; ci < 8; ++ci) {
            int c  = wv * 64 + ci * 8 + cp * 2;      // even
            int cs = c ^ swz;                        // bit0 preserved
            const float* xc0 = xb + (size_t)c * (HH * WW) + wq * 16 + jj;
            const float* xc1 = xc0 + HH * WW;
            #pragma unroll
            for (int r = 0; r < 3; ++r) {
                int y = h - 1 + r;
                float v0 = 0.f, v1 = 0.f;
                if (y >= 0 && y < HH) { v0 = xc0[y * WW]; v1 = xc1[y * WW]; }
                fp16x2 p = __builtin_amdgcn_cvt_pkrtz(v0, v1);
                *(fp16x2*)&xs[(r * SJ + j) * 128 + cs] = p;
            }
        }
        // halo cols j in {0,1,18,19} (xcol = 16wq + {-2,-1,16,17})
        for (int i = t; i < 3 * 4 * 128; i += 128) {
            int jh = i & 3;
            int c  = (i >> 2) & 127;
            int r  = i >> 9;
            int j2 = (jh < 2) ? jh : 16 + jh;
            int xcol = wq * 16 + j2 - 2;
            int y = h - 1 + r;
            float v = (xcol >= 0 && xcol < WW && y >= 0 && y < HH)
                    ? xb[(size_t)c * (HH * WW) + y * WW + xcol] : 0.f;
            xs[(r * SJ + j2) * 128 + (c ^ ((j2 & 15) << 3))] = (_Float16)v;
        }
    }
    __syncthreads();

#define LOADC(BUF, I8) do {                                            \
    int c_ = (I8) * 16 + cw;                                           \
    const float* xc_ = xb + (size_t)c_ * (HH * WW);                    \
    _Pragma("unroll")                                                  \
    for (int di = 0; di < 5; ++di)                                     \
        _Pragma("unroll")                                              \
        for (int jx = 0; jx < 3; ++jx)                                 \
            BUF[di * 3 + jx] = *(const float2*)(xc_ + yoff[di] + coff[jx]); \
} while (0)

#define COMPST(BUF, I8) do {                                           \
    float t0 = 0.f, t1 = 0.f;                                          \
    _Pragma("unroll")                                                  \
    for (int di = 0; di < 5; ++di) {                                   \
        float2 x01 = BUF[di * 3 + 0];                                  \
        float2 x23 = BUF[di * 3 + 1];                                  \
        float2 x45 = BUF[di * 3 + 2];                                  \
        x01.x *= msk[di * 3 + 0]; x01.y *= msk[di * 3 + 0];            \
        x23.x *= msk[di * 3 + 1]; x23.y *= msk[di * 3 + 1];            \
        x45.x *= msk[di * 3 + 2]; x45.y *= msk[di * 3 + 2];            \
        t0 += lg[di*5+0].x * x01.x + lg[di*5+1].x * x01.y              \
            + lg[di*5+2].x * x23.x + lg[di*5+3].x * x23.y              \
            + lg[di*5+4].x * x45.x;                                    \
        t1 += lg[di*5+0].y * x01.y + lg[di*5+1].y * x23.x              \
            + lg[di*5+2].y * x23.y + lg[di*5+3].y * x45.x              \
            + lg[di*5+4].y * x45.y;                                    \
    }                                                                  \
    int cs_ = (I8) * 16 + cw;                                          \
    sKT[(2 * pp2) * 136 + cs_]     = f32_to_bf16(t0);                  \
    sKT[(2 * pp2 + 1) * 136 + cs_] = f32_to_bf16(t1);                  \
} while (0)

    // ---- (a) prefetch phase-C chunks 0 and 1 BEFORE conv ----
    float2 bufA[15], bufB[15];
    LOADC(bufA, 0);
    LOADC(bufB, 1);

    // ---- conv1 via MFMA fp16: D[kk][px] = sum_{c,dy,dx} w1*x ----
    int mt = wv;
    floatx4 acc = {0.f, 0.f, 0.f, 0.f};
    #pragma unroll
    for (int dydx = 0; dydx < 9; ++dydx) {
        int r   = dydx / 3;
        int dxm = dydx - 3 * r;
        int j   = fpx + dxm + 1;                 // staged col, 1..18
        int rowbase = (r * SJ + j) * 128;
        int swz = (j & 15) << 3;
        const unsigned short* whb = w1f + (dydx * 2 + mt) * 2048 + lane * 8;
        #pragma unroll
        for (int ks = 0; ks < 4; ++ks) {
            int cb = (ks * 32 + quad * 8) ^ swz;
            half8 A = *(const half8*)(whb + ks * 512);
            half8 B = *(const half8*)&xs[rowbase + cb];
            acc = __builtin_amdgcn_mfma_f32_16x16x32_f16(A, B, acc, 0, 0, 0);
        }
    }
    #pragma unroll
    for (int reg = 0; reg < 4; ++reg) {          // D row = quad*4+reg
        int kk = mt * 16 + quad * 4 + reg;
        if (kk < KK) pk[kk * PXB + fpx] = acc[reg] + b1r[reg];
    }

    // ---- (b) prefetch MFMA2 A-fragments + b2 BEFORE the pk barrier ----
    short8 afr[4][4];
    float  b2r[4][4];
    #pragma unroll
    for (int ks = 0; ks < 4; ++ks)
        #pragma unroll
        for (int mt2 = 0; mt2 < 4; ++mt2)
            afr[ks][mt2] = *(const short8*)&w2o[(size_t)(64*wv + 16*mt2 + fpx) * CC
                                                + ks*32 + quad*8];
    #pragma unroll
    for (int mt2 = 0; mt2 < 4; ++mt2)
        #pragma unroll
        for (int reg = 0; reg < 4; ++reg)
            b2r[mt2][reg] = b2[64*wv + 16*mt2 + quad*4 + reg];

    __syncthreads();   // pk ready; xs dead -> sKT region reusable

    // ---- softmax (in-register, per phase-C thread) ----
    float2 lg[KK];
    #pragma unroll
    for (int k = 0; k < KK; ++k) lg[k] = *(const float2*)&pk[k * PXB + 2 * pp2];
    float m0 = -1e30f, m1 = -1e30f;
    #pragma unroll
    for (int k = 0; k < KK; ++k) { m0 = fmaxf(m0, lg[k].x); m1 = fmaxf(m1, lg[k].y); }
    float s0 = 0.f, s1 = 0.f;
    #pragma unroll
    for (int k = 0; k < KK; ++k) {
        lg[k].x = __expf(lg[k].x - m0); s0 += lg[k].x;
        lg[k].y = __expf(lg[k].y - m1); s1 += lg[k].y;
    }
    float i0 = 1.f / s0, i1 = 1.f / s1;
    #pragma unroll
    for (int k = 0; k < KK; ++k) { lg[k].x *= i0; lg[k].y *= i1; }

    // ---- phase C: 2-deep rotated pipeline (chunks 0/1 already in regs) ----
    COMPST(bufA, 0); LOADC(bufA, 2);
    COMPST(bufB, 1); LOADC(bufB, 3);
    COMPST(bufA, 2); LOADC(bufA, 4);
    COMPST(bufB, 3); LOADC(bufB, 5);
    COMPST(bufA, 4); LOADC(bufA, 6);
    COMPST(bufB, 5); LOADC(bufB, 7);
    COMPST(bufA, 6);
    COMPST(bufB, 7);
    __syncthreads();

    // ---- MFMA2: C[o][px] = sum_c W2s[o][c] * s[c][px] ----
    floatx4 am[4] = {{0.f,0.f,0.f,0.f},{0.f,0.f,0.f,0.f},
                     {0.f,0.f,0.f,0.f},{0.f,0.f,0.f,0.f}};
    #pragma unroll
    for (int ks = 0; ks < 4; ++ks) {
        short8 bf = *(const short8*)&sKT[fpx * 136 + ks*32 + quad*8];
        #pragma unroll
        for (int mt2 = 0; mt2 < 4; ++mt2)
            am[mt2] = __builtin_amdgcn_mfma_f32_16x16x32_bf16(afr[ks][mt2], bf,
                                                              am[mt2], 0, 0, 0);
    }

    // ---- epilogue: D[row=quad*4+reg][col=fpx] + b2, 2x2-replicated write ----
    float* ob = out + (size_t)b * OUTC * (4 * HH * WW);
    int y0 = 2 * h;
    int pxo = wq * 16 + fpx;
    #pragma unroll
    for (int mt2 = 0; mt2 < 4; ++mt2) {
        #pragma unroll
        for (int reg = 0; reg < 4; ++reg) {
            int o = 64*wv + 16*mt2 + quad*4 + reg;
            float v = am[mt2][reg] + b2r[mt2][reg];
            float2 v2 = make_float2(v, v);
            float* r0p = ob + ((size_t)o * (2*HH) + y0) * (2*WW) + 2*pxo;
            *(float2*)(r0p)        = v2;
            *(float2*)(r0p + 2*WW) = v2;
        }
    }
}

// ---------------------------------------------------------------------------
extern "C" void kernel_launch(void* const* d_in, const int* in_sizes, int n_in,
                              void* d_out, int out_size, void* d_ws, size_t ws_size,
                              hipStream_t stream) {
    const float* x  = (const float*)d_in[0];
    const float* w1 = (const float*)d_in[1];
    const float* b1 = (const float*)d_in[2];
    const float* w2 = (const float*)d_in[3];
    const float* b2 = (const float*)d_in[4];
    float* out = (float*)d_out;

    unsigned short* w2o = (unsigned short*)d_ws;               // 32 KB
    unsigned short* w1f = w2o + (size_t)OUTC * CC;             // 72 KB

    prep_kernel<<<(16384 + 36864 + 255) / 256, 256, 0, stream>>>(w2, w1, w2o, w1f);
    fused_kernel<<<BB * HH * 4, 128, 0, stream>>>(x, w1f, w2o, b1, b2, out);
}

// Round 15
// 97.201 us; speedup vs baseline: 1.0708x; 1.0010x over previous
//
#include <hip/hip_runtime.h>
#include <math.h>

// Problem constants
#define BB   4
#define CC   128
#define HH   64
#define WW   64
#define OUTC 128
#define KK   25     // 5x5 attention taps
#define PXB  16     // pixels per block (quarter row)
#define SJ   20     // staged cols: 16 + 4 halo
#define RS   136    // xs row stride in elements (128 c + 8 pad -> 272B = 4 banks mod 32)

typedef __attribute__((ext_vector_type(8))) short short8;   // 8 bf16
typedef _Float16 half8  __attribute__((ext_vector_type(8)));
typedef __fp16   fp16x2 __attribute__((ext_vector_type(2))); // cvt_pkrtz ret
typedef __attribute__((ext_vector_type(4))) float floatx4;  // MFMA acc

__device__ __forceinline__ unsigned short f32_to_bf16(float v) {
    unsigned int u = __float_as_uint(v);
    u += 0x7fffu + ((u >> 16) & 1u);          // RNE
    return (unsigned short)(u >> 16);
}

// ---------------------------------------------------------------------------
// Kernel 0 (prep): identical to round 12 (verified).
//  i < 16384:        w2o[o][c] = bf16( sum_r w2[o, c*4+r] )  (o-major, MFMA A)
//  16384..+36864:    w1f = conv1 weights as fp16 in MFMA A-fragment lane
//                    order: w1f[(((dydx*2+mt)*4+ks)*64+lane)*8+i8]
// ---------------------------------------------------------------------------
__global__ void prep_kernel(const float* __restrict__ w2,
                            const float* __restrict__ w1,
                            unsigned short* __restrict__ w2o,
                            unsigned short* __restrict__ w1f) {
    int i = blockIdx.x * 256 + threadIdx.x;
    if (i < 16384) {
        int o = i >> 7, c = i & 127;
        const float* p = w2 + o * (4 * CC) + c * 4;
        w2o[o * CC + c] = f32_to_bf16(p[0] + p[1] + p[2] + p[3]);
    } else if (i < 16384 + 36864) {
        int f = i - 16384;            // 0..36863
        int i8   = f & 7;
        int lane = (f >> 3) & 63;
        int ks   = (f >> 9) & 3;
        int mt   = (f >> 11) & 1;
        int dydx = f >> 12;           // 0..8
        int kk = mt * 16 + (lane & 15);
        int c  = ks * 32 + (lane >> 4) * 8 + i8;
        float v = (kk < KK) ? w1[(size_t)(kk * CC + c) * 9 + dydx] : 0.f;
        _Float16 hv = (_Float16)v;    // RNE
        w1f[f] = *(unsigned short*)&hv;
    }
}

// ---------------------------------------------------------------------------
// Fused kernel: conv1-as-MFMA(fp16) + softmax + LDS attention + MFMA + store.
// grid 1024 = (b, h, wq): 16-px quarter-row, 128 threads (2 waves).
// BASE = round 12 (best: 94.9; r13 LDS-phaseC and r14 prefetch both failed).
//
// DIAGNOSIS (r10 counters, fresh eyes): VALUBusy 16% + FETCH 5.5MB -> the
// stall is L1/L2 TRANSACTION throughput, not HBM and not latency per se.
// Phase C's 120 scattered global loads/thread (~10 lines each) dominate the
// per-CU line-fetch budget. Occupancy/prefetch levers don't reduce
// transactions -> all were neutral. r13's LDS fix failed on execution
// (240 scalar u16 reads + per-element XOR = no issue-count cut).
//
// THIS ROUND: c-VECTORIZED LDS phase C.
//  - stage 5 rows (h+-2) of x as fp16 once (coalesced f32 reads, 51KB/blk);
//  - phase C thread = (1 px, 8 contiguous c): each of 25 taps is ONE
//    ds_read_b128 (8 fp16) + 8 f32 FMAs (fma_mix folds the f16 cvt).
//    50 b128 LDS reads replace 120 scattered global loads per thread.
//  - row stride 136 elems (272B = 4 banks mod 32): b128 reads land on
//    distinct 4-bank groups -> wave-minimum 8cy, no conflict tax.
//  - conv reads rows 1..3 of the same buffer (rowbase (r+1)*SJ).
//  - fp16-x numerics in phase C proven by r13 (absmax unchanged 0.015625).
// LDS: xs 27.2KB + pk 1.6KB + sKT 4.4KB = 33.2KB -> 4 blocks/CU.
// __launch_bounds__(128,2): 256-reg budget, proven no-spill.
// ---------------------------------------------------------------------------
__global__ __launch_bounds__(128, 2) void fused_kernel(
        const float* __restrict__ x,
        const unsigned short* __restrict__ w1f,
        const unsigned short* __restrict__ w2o,
        const float* __restrict__ b1,
        const float* __restrict__ b2,
        float* __restrict__ out) {
    __shared__ _Float16 xs[5 * SJ * RS];             // 27200 B
    __shared__ float pk[KK * PXB];                   // 1600 B
    __shared__ unsigned short sKT[PXB * RS];         // 4352 B

    // XCD swizzle (1024 % 8 == 0 -> bijective)
    int bid0 = blockIdx.x;
    int bid  = (bid0 & 7) * 128 + (bid0 >> 3);
    int wq = bid & 3;
    int h  = (bid >> 2) & 63;
    int b  = bid >> 8;
    int t  = threadIdx.x;
    int lane = t & 63;
    int wv = t >> 6;                 // 0..1

    const float* xb = x + (size_t)b * CC * (HH * WW);

    // ---- stage x rows h-2..h+2 as fp16, transposed+swizzled ----
    {
        int jj = lane & 15, cp = lane >> 4;
        int j  = jj + 2;
        int swz = (j & 15) << 3;
        #pragma unroll
        for (int ci = 0; ci < 8; ++ci) {
            int c  = wv * 64 + ci * 8 + cp * 2;      // even
            int cs = c ^ swz;                        // bit0 preserved
            const float* xc0 = xb + (size_t)c * (HH * WW) + wq * 16 + jj;
            const float* xc1 = xc0 + HH * WW;
            #pragma unroll
            for (int r = 0; r < 5; ++r) {
                int y = h - 2 + r;
                float v0 = 0.f, v1 = 0.f;
                if (y >= 0 && y < HH) { v0 = xc0[y * WW]; v1 = xc1[y * WW]; }
                fp16x2 p = __builtin_amdgcn_cvt_pkrtz(v0, v1);
                *(fp16x2*)&xs[(r * SJ + j) * RS + cs] = p;
            }
        }
        // halo cols j in {0,1,18,19} (xcol = 16wq + {-2,-1,16,17})
        for (int i = t; i < 5 * 4 * 128; i += 128) {
            int jh = i & 3;
            int c  = (i >> 2) & 127;
            int r  = i >> 9;
            int j2 = (jh < 2) ? jh : 16 + jh;
            int xcol = wq * 16 + j2 - 2;
            int y = h - 2 + r;
            float v = (xcol >= 0 && xcol < WW && y >= 0 && y < HH)
                    ? xb[(size_t)c * (HH * WW) + y * WW + xcol] : 0.f;
            xs[(r * SJ + j2) * RS + (c ^ ((j2 & 15) << 3))] = (_Float16)v;
        }
    }
    __syncthreads();

    // ---- conv1 via MFMA fp16: D[kk][px] = sum_{c,dy,dx} w1*x ----
    int fpx = lane & 15, quad = lane >> 4;
    int mt = wv;
    floatx4 acc = {0.f, 0.f, 0.f, 0.f};
    #pragma unroll
    for (int dydx = 0; dydx < 9; ++dydx) {
        int r   = dydx / 3;                      // 0..2 -> staged row r+1
        int dxm = dydx - 3 * r;
        int j   = fpx + dxm + 1;                 // staged col, 1..18
        int rowbase = ((r + 1) * SJ + j) * RS;
        int swz = (j & 15) << 3;
        const unsigned short* whb = w1f + (dydx * 2 + mt) * 2048 + lane * 8;
        #pragma unroll
        for (int ks = 0; ks < 4; ++ks) {
            int cb = (ks * 32 + quad * 8) ^ swz;
            half8 A = *(const half8*)(whb + ks * 512);
            half8 B = *(const half8*)&xs[rowbase + cb];
            acc = __builtin_amdgcn_mfma_f32_16x16x32_f16(A, B, acc, 0, 0, 0);
        }
    }
    #pragma unroll
    for (int reg = 0; reg < 4; ++reg) {          // D row = quad*4+reg
        int kk = mt * 16 + quad * 4 + reg;
        if (kk < KK) pk[kk * PXB + fpx] = acc[reg] + b1[kk];
    }
    __syncthreads();   // pk ready; xs stays live for phase C

    // ---- phase C: per-thread softmax + c-vector attention from LDS ----
    // thread = (px = t&15, cg = t>>4 -> 8-channel group); 2 c-halves.
    int px = t & 15, cg = t >> 4;

    float lg[KK];
    #pragma unroll
    for (int k = 0; k < KK; ++k) lg[k] = pk[k * PXB + px];   // broadcast reads
    float mx = -1e30f;
    #pragma unroll
    for (int k = 0; k < KK; ++k) mx = fmaxf(mx, lg[k]);
    float sm = 0.f;
    #pragma unroll
    for (int k = 0; k < KK; ++k) { lg[k] = __expf(lg[k] - mx); sm += lg[k]; }
    float inv = 1.f / sm;
    #pragma unroll
    for (int k = 0; k < KK; ++k) lg[k] *= inv;

    #pragma unroll
    for (int chalf = 0; chalf < 2; ++chalf) {
        int c8 = chalf * 64 + cg * 8;
        float s8[8] = {0.f, 0.f, 0.f, 0.f, 0.f, 0.f, 0.f, 0.f};
        #pragma unroll
        for (int di = 0; di < 5; ++di) {
            #pragma unroll
            for (int dj = 0; dj < 5; ++dj) {
                int j = px + dj;                 // staged col (0..19)
                half8 xw = *(const half8*)&xs[(di * SJ + j) * RS
                                              + (c8 ^ ((j & 15) << 3))];
                float pv = lg[di * 5 + dj];
                #pragma unroll
                for (int e = 0; e < 8; ++e)
                    s8[e] += pv * (float)xw[e];  // fma_mix: f16 src, f32 acc
            }
        }
        short8 sv;
        #pragma unroll
        for (int e = 0; e < 8; ++e) sv[e] = (short)f32_to_bf16(s8[e]);
        *(short8*)&sKT[px * RS + c8] = sv;
    }
    __syncthreads();

    // ---- MFMA2: C[o][px] = sum_c W2s[o][c] * s[c][px] ----
    // wave wv owns o-rows [64wv, 64wv+64): 4 o-tiles x 4 ks = 16 MFMA.
    floatx4 am[4] = {{0.f,0.f,0.f,0.f},{0.f,0.f,0.f,0.f},
                     {0.f,0.f,0.f,0.f},{0.f,0.f,0.f,0.f}};
    #pragma unroll
    for (int ks = 0; ks < 4; ++ks) {
        short8 bf = *(const short8*)&sKT[fpx * RS + ks*32 + quad*8];
        #pragma unroll
        for (int mt2 = 0; mt2 < 4; ++mt2) {
            short8 af = *(const short8*)&w2o[(size_t)(64*wv + 16*mt2 + fpx) * CC
                                             + ks*32 + quad*8];
            am[mt2] = __builtin_amdgcn_mfma_f32_16x16x32_bf16(af, bf, am[mt2], 0, 0, 0);
        }
    }

    // ---- epilogue: D[row=quad*4+reg][col=fpx] + b2, 2x2-replicated write ----
    float* ob = out + (size_t)b * OUTC * (4 * HH * WW);
    int y0 = 2 * h;
    int pxo = wq * 16 + fpx;
    #pragma unroll
    for (int mt2 = 0; mt2 < 4; ++mt2) {
        #pragma unroll
        for (int reg = 0; reg < 4; ++reg) {
            int o = 64*wv + 16*mt2 + quad*4 + reg;
            float v = am[mt2][reg] + b2[o];
            float2 v2 = make_float2(v, v);
            float* r0p = ob + ((size_t)o * (2*HH) + y0) * (2*WW) + 2*pxo;
            *(float2*)(r0p)        = v2;
            *(float2*)(r0p + 2*WW) = v2;
        }
    }
}

// ---------------------------------------------------------------------------
extern "C" void kernel_launch(void* const* d_in, const int* in_sizes, int n_in,
                              void* d_out, int out_size, void* d_ws, size_t ws_size,
                              hipStream_t stream) {
    const float* x  = (const float*)d_in[0];
    const float* w1 = (const float*)d_in[1];
    const float* b1 = (const float*)d_in[2];
    const float* w2 = (const float*)d_in[3];
    const float* b2 = (const float*)d_in[4];
    float* out = (float*)d_out;

    unsigned short* w2o = (unsigned short*)d_ws;               // 32 KB
    unsigned short* w1f = w2o + (size_t)OUTC * CC;             // 72 KB

    prep_kernel<<<(16384 + 36864 + 255) / 256, 256, 0, stream>>>(w2, w1, w2o, w1f);
    fused_kernel<<<BB * HH * 4, 128, 0, stream>>>(x, w1f, w2o, b1, b2, out);
}

// Round 16
// 94.533 us; speedup vs baseline: 1.1010x; 1.0282x over previous
//
#include <hip/hip_runtime.h>
#include <math.h>

// Problem constants
#define BB   4
#define CC   128
#define HH   64
#define WW   64
#define OUTC 128
#define KK   25     // 5x5 attention taps
#define PXB  16     // pixels per block (quarter row)
#define SJ   20     // staged cols: 16 + 4 halo

typedef __attribute__((ext_vector_type(8))) short short8;   // 8 bf16
typedef _Float16 half8  __attribute__((ext_vector_type(8)));
typedef __fp16   fp16x2 __attribute__((ext_vector_type(2))); // cvt_pkrtz ret
typedef __attribute__((ext_vector_type(4))) float floatx4;  // MFMA acc

__device__ __forceinline__ unsigned short f32_to_bf16(float v) {
    unsigned int u = __float_as_uint(v);
    u += 0x7fffu + ((u >> 16) & 1u);          // RNE
    return (unsigned short)(u >> 16);
}

// ---------------------------------------------------------------------------
// Kernel 0 (prep): identical to round 12 (verified).
//  i < 16384:        w2o[o][c] = bf16( sum_r w2[o, c*4+r] )  (o-major, MFMA A)
//  16384..+36864:    w1f = conv1 weights as fp16 in MFMA A-fragment lane
//                    order: w1f[(((dydx*2+mt)*4+ks)*64+lane)*8+i8]
// ---------------------------------------------------------------------------
__global__ void prep_kernel(const float* __restrict__ w2,
                            const float* __restrict__ w1,
                            unsigned short* __restrict__ w2o,
                            unsigned short* __restrict__ w1f) {
    int i = blockIdx.x * 256 + threadIdx.x;
    if (i < 16384) {
        int o = i >> 7, c = i & 127;
        const float* p = w2 + o * (4 * CC) + c * 4;
        w2o[o * CC + c] = f32_to_bf16(p[0] + p[1] + p[2] + p[3]);
    } else if (i < 16384 + 36864) {
        int f = i - 16384;            // 0..36863
        int i8   = f & 7;
        int lane = (f >> 3) & 63;
        int ks   = (f >> 9) & 3;
        int mt   = (f >> 11) & 1;
        int dydx = f >> 12;           // 0..8
        int kk = mt * 16 + (lane & 15);
        int c  = ks * 32 + (lane >> 4) * 8 + i8;
        float v = (kk < KK) ? w1[(size_t)(kk * CC + c) * 9 + dydx] : 0.f;
        _Float16 hv = (_Float16)v;    // RNE
        w1f[f] = *(unsigned short*)&hv;
    }
}

// ---------------------------------------------------------------------------
// Fused kernel: conv1-as-MFMA(fp16) + softmax + attention + MFMA + 2x2 store.
// grid 1024 = (b, h, wq): 16-px quarter-row, 128 threads (2 waves).
// BASE = round 12 (best 94.9; r13/r14/r15 phase-C & prefetch probes all
// neutral -> phase C exonerated; remaining theory = serialized load drains).
//
// THIS ROUND: break the dependent-latency chains.
//  1. Staging two-pass: ALL 48 global loads batched into registers
//     (unconditional clamped addresses, uniform row masks at pack time),
//     THEN 24 cvt_pkrtz + ds_write. One vmcnt drain instead of ~24
//     serialized load->pack->write round-trips.
//  2. Halo two-pass: 12 scattered loads batched, then 12 ds_writes.
//  3. Conv dual accumulator (even/odd dydx): two independent MFMA chains
//     interleave -> MFMA latency hidden (f32 reassociation only; r10
//     proved tolerance-safe).
// LDS: xs 15KB + pk 1.6KB = 17KB; sKT overlays xs after conv.
// __launch_bounds__(128,2): 256-reg budget, proven no-spill.
// ---------------------------------------------------------------------------
__global__ __launch_bounds__(128, 2) void fused_kernel(
        const float* __restrict__ x,
        const unsigned short* __restrict__ w1f,
        const unsigned short* __restrict__ w2o,
        const float* __restrict__ b1,
        const float* __restrict__ b2,
        float* __restrict__ out) {
    __shared__ _Float16 xs[3 * SJ * 128];            // 15360 B
    __shared__ float pk[KK * PXB];                   // 1600 B
    unsigned short* sKT = (unsigned short*)xs;       // 16x136 bf16 overlay

    // XCD swizzle (1024 % 8 == 0 -> bijective)
    int bid0 = blockIdx.x;
    int bid  = (bid0 & 7) * 128 + (bid0 >> 3);
    int wq = bid & 3;
    int h  = (bid >> 2) & 63;
    int b  = bid >> 8;
    int t  = threadIdx.x;
    int lane = t & 63;
    int wv = t >> 6;                 // 0..1

    const float* xb = x + (size_t)b * CC * (HH * WW);

    // ---- stage x rows h-1..h+1 as fp16, transposed+swizzled (2-pass) ----
    {
        int jj = lane & 15, cp = lane >> 4;
        int j  = jj + 2;
        int swz = (j & 15) << 3;
        float mr_[3]; int yo_[3];
        #pragma unroll
        for (int r = 0; r < 3; ++r) {
            int y = h - 1 + r;
            mr_[r] = (y >= 0 && y < HH) ? 1.f : 0.f;
            yo_[r] = min(max(y, 0), HH - 1) * WW;
        }
        // pass 1: batch all 48 loads (24 channel-pairs x 3 rows)
        float v0s[24], v1s[24];
        #pragma unroll
        for (int ci = 0; ci < 8; ++ci) {
            int c = wv * 64 + ci * 8 + cp * 2;       // even
            const float* xc0 = xb + (size_t)c * (HH * WW) + wq * 16 + jj;
            const float* xc1 = xc0 + HH * WW;
            #pragma unroll
            for (int r = 0; r < 3; ++r) {
                v0s[ci * 3 + r] = xc0[yo_[r]];
                v1s[ci * 3 + r] = xc1[yo_[r]];
            }
        }
        // pass 2: pack + LDS write
        #pragma unroll
        for (int ci = 0; ci < 8; ++ci) {
            int c  = wv * 64 + ci * 8 + cp * 2;
            int cs = c ^ swz;                        // bit0 preserved
            #pragma unroll
            for (int r = 0; r < 3; ++r) {
                fp16x2 p = __builtin_amdgcn_cvt_pkrtz(
                    v0s[ci * 3 + r] * mr_[r], v1s[ci * 3 + r] * mr_[r]);
                *(fp16x2*)&xs[(r * SJ + j) * 128 + cs] = p;
            }
        }
        // halo cols j in {0,1,18,19} (xcol = 16wq + {-2,-1,16,17}) — 2-pass
        float hv[12], hm[12];
        #pragma unroll
        for (int k = 0; k < 12; ++k) {
            int i  = t + k * 128;
            int jh = i & 3;
            int c  = (i >> 2) & 127;
            int r  = i >> 9;
            int j2 = (jh < 2) ? jh : 16 + jh;
            int xcol = wq * 16 + j2 - 2;
            int y = h - 1 + r;
            bool inb = (xcol >= 0 && xcol < WW && y >= 0 && y < HH);
            int yc  = min(max(y, 0), HH - 1);
            int xc2 = min(max(xcol, 0), WW - 1);
            hv[k] = xb[(size_t)c * (HH * WW) + yc * WW + xc2];
            hm[k] = inb ? 1.f : 0.f;
        }
        #pragma unroll
        for (int k = 0; k < 12; ++k) {
            int i  = t + k * 128;
            int jh = i & 3;
            int c  = (i >> 2) & 127;
            int r  = i >> 9;
            int j2 = (jh < 2) ? jh : 16 + jh;
            xs[(r * SJ + j2) * 128 + (c ^ ((j2 & 15) << 3))] =
                (_Float16)(hv[k] * hm[k]);
        }
    }
    __syncthreads();

    // ---- conv1 via MFMA fp16, dual accumulator chains ----
    int fpx = lane & 15, quad = lane >> 4;
    int mt = wv;
    floatx4 acc0 = {0.f, 0.f, 0.f, 0.f};
    floatx4 acc1 = {0.f, 0.f, 0.f, 0.f};
    #pragma unroll
    for (int dydx = 0; dydx < 9; ++dydx) {
        int r   = dydx / 3;
        int dxm = dydx - 3 * r;
        int j   = fpx + dxm + 1;                 // staged col, 1..18
        int rowbase = (r * SJ + j) * 128;
        int swz = (j & 15) << 3;
        const unsigned short* whb = w1f + (dydx * 2 + mt) * 2048 + lane * 8;
        floatx4& accr = (dydx & 1) ? acc1 : acc0;   // static under unroll
        #pragma unroll
        for (int ks = 0; ks < 4; ++ks) {
            int cb = (ks * 32 + quad * 8) ^ swz;
            half8 A = *(const half8*)(whb + ks * 512);
            half8 B = *(const half8*)&xs[rowbase + cb];
            accr = __builtin_amdgcn_mfma_f32_16x16x32_f16(A, B, accr, 0, 0, 0);
        }
    }
    floatx4 accs = acc0 + acc1;
    #pragma unroll
    for (int reg = 0; reg < 4; ++reg) {          // D row = quad*4+reg
        int kk = mt * 16 + quad * 4 + reg;
        if (kk < KK) pk[kk * PXB + fpx] = accs[reg] + b1[kk];
    }
    __syncthreads();   // pk ready; xs dead -> sKT region reusable

    // ---- phase C: in-register softmax + pipelined attention (r12) ----
    // thread = (pp2 = t&7 -> px {2pp2, 2pp2+1}, cw = t>>3 -> 8 chunks of c)
    int pp2 = t & 7, cw = t >> 3;

    float2 lg[KK];
    #pragma unroll
    for (int k = 0; k < KK; ++k) lg[k] = *(const float2*)&pk[k * PXB + 2 * pp2];
    float m0 = -1e30f, m1 = -1e30f;
    #pragma unroll
    for (int k = 0; k < KK; ++k) { m0 = fmaxf(m0, lg[k].x); m1 = fmaxf(m1, lg[k].y); }
    float s0 = 0.f, s1 = 0.f;
    #pragma unroll
    for (int k = 0; k < KK; ++k) {
        lg[k].x = __expf(lg[k].x - m0); s0 += lg[k].x;
        lg[k].y = __expf(lg[k].y - m1); s1 += lg[k].y;
    }
    float i0 = 1.f / s0, i1 = 1.f / s1;
    #pragma unroll
    for (int k = 0; k < KK; ++k) { lg[k].x *= i0; lg[k].y *= i1; }

    int colg = wq * 16 + 2 * pp2 - 2;
    int coff[3]; float cmask[3];
    #pragma unroll
    for (int jx = 0; jx < 3; ++jx) {
        int cg = colg + 2 * jx;
        cmask[jx] = (cg >= 0 && cg <= WW - 2) ? 1.f : 0.f;
        coff[jx]  = min(max(cg, 0), WW - 2);
    }
    int yoff[5]; float msk[15];
    #pragma unroll
    for (int di = 0; di < 5; ++di) {
        int y = h + di - 2;
        float rm = (y >= 0 && y < HH) ? 1.f : 0.f;
        yoff[di] = min(max(y, 0), HH - 1) * WW;
        #pragma unroll
        for (int jx = 0; jx < 3; ++jx) msk[di * 3 + jx] = rm * cmask[jx];
    }

#define LOADC(BUF, I8) do {                                            \
    int c_ = (I8) * 16 + cw;                                           \
    const float* xc_ = xb + (size_t)c_ * (HH * WW);                    \
    _Pragma("unroll")                                                  \
    for (int di = 0; di < 5; ++di)                                     \
        _Pragma("unroll")                                              \
        for (int jx = 0; jx < 3; ++jx)                                 \
            BUF[di * 3 + jx] = *(const float2*)(xc_ + yoff[di] + coff[jx]); \
} while (0)

#define COMPST(BUF, I8) do {                                           \
    float t0 = 0.f, t1 = 0.f;                                          \
    _Pragma("unroll")                                                  \
    for (int di = 0; di < 5; ++di) {                                   \
        float2 x01 = BUF[di * 3 + 0];                                  \
        float2 x23 = BUF[di * 3 + 1];                                  \
        float2 x45 = BUF[di * 3 + 2];                                  \
        x01.x *= msk[di * 3 + 0]; x01.y *= msk[di * 3 + 0];            \
        x23.x *= msk[di * 3 + 1]; x23.y *= msk[di * 3 + 1];            \
        x45.x *= msk[di * 3 + 2]; x45.y *= msk[di * 3 + 2];            \
        t0 += lg[di*5+0].x * x01.x + lg[di*5+1].x * x01.y              \
            + lg[di*5+2].x * x23.x + lg[di*5+3].x * x23.y              \
            + lg[di*5+4].x * x45.x;                                    \
        t1 += lg[di*5+0].y * x01.y + lg[di*5+1].y * x23.x              \
            + lg[di*5+2].y * x23.y + lg[di*5+3].y * x45.x              \
            + lg[di*5+4].y * x45.y;                                    \
    }                                                                  \
    int cs_ = (I8) * 16 + cw;                                          \
    sKT[(2 * pp2) * 136 + cs_]     = f32_to_bf16(t0);                  \
    sKT[(2 * pp2 + 1) * 136 + cs_] = f32_to_bf16(t1);                  \
} while (0)

    {
        float2 bufA[15], bufB[15];
        LOADC(bufA, 0);
        LOADC(bufB, 1);
        COMPST(bufA, 0); LOADC(bufA, 2);
        COMPST(bufB, 1); LOADC(bufB, 3);
        COMPST(bufA, 2); LOADC(bufA, 4);
        COMPST(bufB, 3); LOADC(bufB, 5);
        COMPST(bufA, 4); LOADC(bufA, 6);
        COMPST(bufB, 5); LOADC(bufB, 7);
        COMPST(bufA, 6);
        COMPST(bufB, 7);
    }
    __syncthreads();

    // ---- MFMA2: C[o][px] = sum_c W2s[o][c] * s[c][px] ----
    // wave wv owns o-rows [64wv, 64wv+64): 4 o-tiles x 4 ks = 16 MFMA.
    floatx4 am[4] = {{0.f,0.f,0.f,0.f},{0.f,0.f,0.f,0.f},
                     {0.f,0.f,0.f,0.f},{0.f,0.f,0.f,0.f}};
    #pragma unroll
    for (int ks = 0; ks < 4; ++ks) {
        short8 bf = *(const short8*)&sKT[fpx * 136 + ks*32 + quad*8];
        #pragma unroll
        for (int mt2 = 0; mt2 < 4; ++mt2) {
            short8 af = *(const short8*)&w2o[(size_t)(64*wv + 16*mt2 + fpx) * CC
                                             + ks*32 + quad*8];
            am[mt2] = __builtin_amdgcn_mfma_f32_16x16x32_bf16(af, bf, am[mt2], 0, 0, 0);
        }
    }

    // ---- epilogue: D[row=quad*4+reg][col=fpx] + b2, 2x2-replicated write ----
    float* ob = out + (size_t)b * OUTC * (4 * HH * WW);
    int y0 = 2 * h;
    int pxo = wq * 16 + fpx;
    #pragma unroll
    for (int mt2 = 0; mt2 < 4; ++mt2) {
        #pragma unroll
        for (int reg = 0; reg < 4; ++reg) {
            int o = 64*wv + 16*mt2 + quad*4 + reg;
            float v = am[mt2][reg] + b2[o];
            float2 v2 = make_float2(v, v);
            float* r0p = ob + ((size_t)o * (2*HH) + y0) * (2*WW) + 2*pxo;
            *(float2*)(r0p)        = v2;
            *(float2*)(r0p + 2*WW) = v2;
        }
    }
}

// ---------------------------------------------------------------------------
extern "C" void kernel_launch(void* const* d_in, const int* in_sizes, int n_in,
                              void* d_out, int out_size, void* d_ws, size_t ws_size,
                              hipStream_t stream) {
    const float* x  = (const float*)d_in[0];
    const float* w1 = (const float*)d_in[1];
    const float* b1 = (const float*)d_in[2];
    const float* w2 = (const float*)d_in[3];
    const float* b2 = (const float*)d_in[4];
    float* out = (float*)d_out;

    unsigned short* w2o = (unsigned short*)d_ws;               // 32 KB
    unsigned short* w1f = w2o + (size_t)OUTC * CC;             // 72 KB

    prep_kernel<<<(16384 + 36864 + 255) / 256, 256, 0, stream>>>(w2, w1, w2o, w1f);
    fused_kernel<<<BB * HH * 4, 128, 0, stream>>>(x, w1f, w2o, b1, b2, out);
}